// Round 14
// baseline (283.288 us; speedup 1.0000x reference)
//
#include <hip/hip_runtime.h>
#include <hip/hip_bf16.h>

#define FIN 78
#define CDIM 128
#define HEADS 10
#define HC 1280
#define GRAPHS 64
#define KP 96   // padded K for layer-1

typedef __bf16 bf16x8 __attribute__((ext_vector_type(8)));
typedef __bf16 bf16x2 __attribute__((ext_vector_type(2)));
typedef float f32x4 __attribute__((ext_vector_type(4)));

// ---------------- init: zero bufs + pack xb/W1t/W2t ----------------
__global__ void init_kernel(unsigned* counts, unsigned* cursor, unsigned* pooled_u,
                            float* as1, float* ad1,
                            const float* __restrict__ x, __bf16* __restrict__ xb,
                            const float* __restrict__ W1, __bf16* __restrict__ W1t,
                            const float* __restrict__ W2, __bf16* __restrict__ W2t,
                            int N, int Mpad) {
    int t = blockIdx.x * 256 + threadIdx.x;
    if (t < N) { counts[t] = 0u; cursor[t] = 0u; }
    if (t < GRAPHS * CDIM) pooled_u[t] = 0x007FFFFFu;  // enc(-inf)
    if (t < N * HEADS) { as1[t] = 0.f; ad1[t] = 0.f; }
    if (t < Mpad * KP) {
        int m = t / KP, k = t % KP;
        float v = (m < N && k < FIN) ? x[(size_t)m * FIN + k] : 0.f;
        xb[t] = (__bf16)v;
    }
    if (t < HC * KP) {
        int n = t / KP, k = t % KP;
        float v = (k < FIN) ? W1[(size_t)k * HC + n] : 0.f;
        W1t[t] = (__bf16)v;
    }
    if (t < CDIM * HC) {
        int n = t / HC, k = t % HC;
        W2t[t] = (__bf16)W2[(size_t)k * CDIM + n];
    }
}

// histogram MUST be a separate launch: it reads counts zeroed by init_kernel.
__global__ void hist_kernel(const int* __restrict__ ei, int E, unsigned* counts) {
    int e = blockIdx.x * 256 + threadIdx.x;
    if (e < E) atomicAdd(&counts[ei[E + e]], 1u);
}

// ---------------- layer-1 GEMM: 128x128x96 bf16 MFMA + fused scores + LDS-staged store
__global__ __launch_bounds__(256) void gemm1_mfma_kernel(
        const __bf16* __restrict__ xb, const __bf16* __restrict__ W1t,
        const float* __restrict__ asrc, const float* __restrict__ adst,
        __bf16* __restrict__ h1pb, float* __restrict__ as1, float* __restrict__ ad1,
        int M) {
    __shared__ __align__(16) __bf16 smem[2 * 128 * 104];   // A/B staging; reused for C
    auto Alds = (__bf16 (*)[104])smem;
    auto Blds = (__bf16 (*)[104])(smem + 128 * 104);
    const int tid = threadIdx.x;
    const int wave = tid >> 6, lane = tid & 63;
    const int wr = wave >> 1, wc = wave & 1;
    const int m0 = blockIdx.x * 128;
    const int head = blockIdx.y;
    const int n0 = head * CDIM;
    const int fl = lane & 15;
    const int fh = lane >> 4;

    for (int idx = tid; idx < 128 * 12; idx += 256) {
        int r = idx / 12, ks = (idx % 12) * 8;
        *(bf16x8*)&Alds[r][ks] = *(const bf16x8*)(xb + (size_t)(m0 + r) * KP + ks);
        *(bf16x8*)&Blds[r][ks] = *(const bf16x8*)(W1t + (size_t)(n0 + r) * KP + ks);
    }
    __syncthreads();

    f32x4 acc[4][4] = {};
    #pragma unroll
    for (int ks = 0; ks < KP; ks += 32) {
        bf16x8 a[4], b[4];
        #pragma unroll
        for (int t = 0; t < 4; ++t) {
            a[t] = *(const bf16x8*)&Alds[wr * 64 + t * 16 + fl][ks + fh * 8];
            b[t] = *(const bf16x8*)&Blds[wc * 64 + t * 16 + fl][ks + fh * 8];
        }
        #pragma unroll
        for (int i = 0; i < 4; ++i)
            #pragma unroll
            for (int j = 0; j < 4; ++j)
                acc[i][j] = __builtin_amdgcn_mfma_f32_16x16x32_bf16(a[i], b[j], acc[i][j], 0, 0, 0);
    }

    float a_s[4], a_d[4];
    #pragma unroll
    for (int j = 0; j < 4; ++j) {
        int gn = n0 + wc * 64 + j * 16 + fl;
        a_s[j] = asrc[gn];
        a_d[j] = adst[gn];
    }
    #pragma unroll
    for (int i = 0; i < 4; ++i) {
        #pragma unroll
        for (int r = 0; r < 4; ++r) {
            int gm = m0 + wr * 64 + i * 16 + fh * 4 + r;
            float vs = 0.f, vd = 0.f;
            #pragma unroll
            for (int j = 0; j < 4; ++j) {
                vs += acc[i][j][r] * a_s[j];
                vd += acc[i][j][r] * a_d[j];
            }
            #pragma unroll
            for (int off = 1; off < 16; off <<= 1) {
                vs += __shfl_xor(vs, off);
                vd += __shfl_xor(vd, off);
            }
            if (fl == 0 && gm < M) {
                atomicAdd(&as1[gm * HEADS + head], vs);
                atomicAdd(&ad1[gm * HEADS + head], vd);
            }
        }
    }

    __syncthreads();
    auto Cst = (__bf16 (*)[136])smem;
    #pragma unroll
    for (int i = 0; i < 4; ++i)
        #pragma unroll
        for (int j = 0; j < 4; ++j)
            #pragma unroll
            for (int r = 0; r < 4; ++r)
                Cst[wr * 64 + i * 16 + fh * 4 + r][wc * 64 + j * 16 + fl] = (__bf16)acc[i][j][r];
    __syncthreads();
    for (int idx = tid; idx < 128 * 16; idx += 256) {
        int r = idx >> 4, v = (idx & 15) * 8;
        int gm = m0 + r;
        if (gm < M)
            *(bf16x8*)(h1pb + (size_t)gm * HC + n0 + v) = *(const bf16x8*)&Cst[r][v];
    }
}

// ---------------- layer-2 GEMM: BM=64, BN=128 (full width), split-K=2 ----------------
// A-tile read once per (m0,z); B (W2t) L2-resident. LDS-staged coalesced f32 stores.
__global__ __launch_bounds__(256) void gemm2_mfma_kernel(
        const __bf16* __restrict__ A, const __bf16* __restrict__ W2t,
        float* __restrict__ Cpart, int M) {
    constexpr int BK = 64;
    constexpr int KCHUNK = HC / 2;  // 640
    // union: staging (64+128) rows x 72 bf16 = 27648 B; epilogue 64 x 132 f32 = 33792 B
    __shared__ __align__(16) float smemf[64 * 132];
    __bf16* smem = (__bf16*)smemf;
    auto Alds = (__bf16 (*)[72])smem;
    auto Blds = (__bf16 (*)[72])(smem + 64 * 72);
    const int tid = threadIdx.x;
    const int wave = tid >> 6, lane = tid & 63;
    const int wr = wave >> 1, wc = wave & 1;
    const int m0 = blockIdx.x * 64;
    const int kbase = blockIdx.z * KCHUNK;

    const int kslot = (tid & 7) * 8;
    const int srow  = tid >> 3;
    const int fl = lane & 15;
    const int fh = lane >> 4;

    f32x4 acc[2][4] = {};

    for (int k0 = kbase; k0 < kbase + KCHUNK; k0 += BK) {
        #pragma unroll
        for (int rp = 0; rp < 2; ++rp) {
            int r = srow + rp * 32;
            int gm = m0 + r;
            bf16x8 va = {};
            if (gm < M) va = *(const bf16x8*)(A + (size_t)gm * HC + k0 + kslot);
            *(bf16x8*)&Alds[r][kslot] = va;
        }
        #pragma unroll
        for (int rp = 0; rp < 4; ++rp) {
            int r = srow + rp * 32;
            *(bf16x8*)&Blds[r][kslot] = *(const bf16x8*)(W2t + (size_t)r * HC + k0 + kslot);
        }
        __syncthreads();
        #pragma unroll
        for (int ks = 0; ks < BK; ks += 32) {
            bf16x8 a[2], b[4];
            #pragma unroll
            for (int t = 0; t < 2; ++t)
                a[t] = *(const bf16x8*)&Alds[wr * 32 + t * 16 + fl][ks + fh * 8];
            #pragma unroll
            for (int t = 0; t < 4; ++t)
                b[t] = *(const bf16x8*)&Blds[wc * 64 + t * 16 + fl][ks + fh * 8];
            #pragma unroll
            for (int i = 0; i < 2; ++i)
                #pragma unroll
                for (int j = 0; j < 4; ++j)
                    acc[i][j] = __builtin_amdgcn_mfma_f32_16x16x32_bf16(a[i], b[j], acc[i][j], 0, 0, 0);
        }
        __syncthreads();
    }
    auto CstF = (float (*)[132])smemf;
    #pragma unroll
    for (int i = 0; i < 2; ++i)
        #pragma unroll
        for (int j = 0; j < 4; ++j)
            #pragma unroll
            for (int r = 0; r < 4; ++r)
                CstF[wr * 32 + i * 16 + fh * 4 + r][wc * 64 + j * 16 + fl] = acc[i][j][r];
    __syncthreads();
    float* base = Cpart + (size_t)blockIdx.z * M * CDIM;
    for (int idx = tid; idx < 64 * 32; idx += 256) {
        int r = idx >> 5, c = (idx & 31) * 4;
        int gm = m0 + r;
        if (gm < M)
            *(f32x4*)(base + (size_t)gm * CDIM + c) = *(const f32x4*)&CstF[r][c];
    }
}

// ---------------- combine split-K partials -> h2b (bf16) + exact scores2 -------------
__global__ __launch_bounds__(256) void combine_kernel(
        const float* __restrict__ Cpart, const float* __restrict__ asrc2,
        const float* __restrict__ adst2, __bf16* __restrict__ h2b,
        float* __restrict__ as2, float* __restrict__ ad2, int N) {
    const int lane = threadIdx.x & 63, wave = threadIdx.x >> 6;
    const int n = blockIdx.x * 4 + wave;
    if (n >= N) return;
    const float* p0 = Cpart + (size_t)n * CDIM;
    const float* p1 = Cpart + (size_t)(N + n) * CDIM;
    float v0 = p0[lane] + p1[lane];
    float v1 = p0[lane + 64] + p1[lane + 64];
    h2b[(size_t)n * CDIM + lane] = (__bf16)v0;
    h2b[(size_t)n * CDIM + lane + 64] = (__bf16)v1;
    float vs = v0 * asrc2[lane] + v1 * asrc2[lane + 64];
    float vd = v0 * adst2[lane] + v1 * adst2[lane + 64];
    #pragma unroll
    for (int off = 32; off; off >>= 1) {
        vs += __shfl_xor(vs, off);
        vd += __shfl_xor(vd, off);
    }
    if (lane == 0) { as2[n] = vs; ad2[n] = vd; }
}

// ---------------- CSR build ----------------
__global__ void scan_kernel(const unsigned* __restrict__ counts, unsigned* __restrict__ offsets, int n) {
    __shared__ unsigned part[1024];
    int t = threadIdx.x;
    int chunk = (n + 1023) / 1024;
    int lo = t * chunk, hi = min(lo + chunk, n);
    unsigned s = 0;
    for (int i = lo; i < hi; ++i) s += counts[i] + 1u;   // +1 self-loop per node
    part[t] = s;
    __syncthreads();
    for (int d = 1; d < 1024; d <<= 1) {
        unsigned v = (t >= d) ? part[t - d] : 0u;
        __syncthreads();
        part[t] += v;
        __syncthreads();
    }
    unsigned base = (t == 0) ? 0u : part[t - 1];
    for (int i = lo; i < hi; ++i) { offsets[i] = base; base += counts[i] + 1u; }
    if (t == 1023) offsets[n] = part[1023];
}

__global__ void scatter_kernel(const int* __restrict__ ei, int E, int N,
                               const unsigned* __restrict__ offsets, unsigned* cursor,
                               int2* __restrict__ csr2) {
    int e = blockIdx.x * 256 + threadIdx.x;
    int Et = E + N;
    if (e >= Et) return;
    int s, d;
    if (e < E) { s = ei[e]; d = ei[E + e]; } else { s = e - E; d = e - E; }
    unsigned pos = offsets[d] + atomicAdd(&cursor[d], 1u);
    csr2[pos] = make_int2(s, e);
}

// ---------------- segment softmax L1: one wave per node ----------------
__global__ __launch_bounds__(256) void softmax1_kernel(
        const unsigned* __restrict__ offsets, const int2* __restrict__ csr2,
        const float* __restrict__ as1, const float* __restrict__ ad1,
        float* __restrict__ alpha_out, float* __restrict__ alpha_csr, int N) {
    const int wave = threadIdx.x >> 6, lane = threadIdx.x & 63;
    const int n = blockIdx.x * 4 + wave;
    if (n >= N) return;
    const unsigned p0 = offsets[n], p1 = offsets[n + 1];
    const unsigned deg = p1 - p0;

    float adn[HEADS];
    #pragma unroll
    for (int h = 0; h < HEADS; ++h) adn[h] = ad1[n * HEADS + h];

    if (deg <= 64) {
        const bool act = lane < (int)deg;
        const unsigned p = p0 + lane;
        int s = 0, eid = 0;
        if (act) { int2 se = csr2[p]; s = se.x; eid = se.y; }
        const float* arow = as1 + (size_t)s * HEADS;
        float e[HEADS];
        #pragma unroll
        for (int h = 0; h < HEADS; ++h) {
            float v = act ? (arow[h] + adn[h]) : -INFINITY;
            e[h] = (v >= 0.f) ? v : 0.2f * v;
        }
        float m[HEADS];
        #pragma unroll
        for (int h = 0; h < HEADS; ++h) m[h] = e[h];
        #pragma unroll
        for (int off = 32; off; off >>= 1)
            #pragma unroll
            for (int h = 0; h < HEADS; ++h) m[h] = fmaxf(m[h], __shfl_xor(m[h], off));
        float ex[HEADS], sm[HEADS];
        #pragma unroll
        for (int h = 0; h < HEADS; ++h) {
            ex[h] = act ? __expf(e[h] - m[h]) : 0.f;
            sm[h] = ex[h];
        }
        #pragma unroll
        for (int off = 32; off; off >>= 1)
            #pragma unroll
            for (int h = 0; h < HEADS; ++h) sm[h] += __shfl_xor(sm[h], off);
        if (act) {
            #pragma unroll
            for (int h = 0; h < HEADS; ++h) {
                float a = ex[h] / (sm[h] + 1e-16f);
                alpha_csr[(size_t)p * HEADS + h] = a;
                alpha_out[(size_t)eid * HEADS + h] = a;
            }
        }
    } else {
        float m[HEADS];
        #pragma unroll
        for (int h = 0; h < HEADS; ++h) m[h] = -INFINITY;
        for (unsigned p = p0 + lane; p < p1; p += 64) {
            const float* arow = as1 + (size_t)csr2[p].x * HEADS;
            #pragma unroll
            for (int h = 0; h < HEADS; ++h) {
                float v = arow[h] + adn[h];
                v = (v >= 0.f) ? v : 0.2f * v;
                m[h] = fmaxf(m[h], v);
            }
        }
        #pragma unroll
        for (int off = 32; off; off >>= 1)
            #pragma unroll
            for (int h = 0; h < HEADS; ++h) m[h] = fmaxf(m[h], __shfl_xor(m[h], off));
        float sm[HEADS];
        #pragma unroll
        for (int h = 0; h < HEADS; ++h) sm[h] = 0.f;
        for (unsigned p = p0 + lane; p < p1; p += 64) {
            const float* arow = as1 + (size_t)csr2[p].x * HEADS;
            #pragma unroll
            for (int h = 0; h < HEADS; ++h) {
                float v = arow[h] + adn[h];
                v = (v >= 0.f) ? v : 0.2f * v;
                sm[h] += __expf(v - m[h]);
            }
        }
        #pragma unroll
        for (int off = 32; off; off >>= 1)
            #pragma unroll
            for (int h = 0; h < HEADS; ++h) sm[h] += __shfl_xor(sm[h], off);
        float inv[HEADS];
        #pragma unroll
        for (int h = 0; h < HEADS; ++h) inv[h] = 1.f / (sm[h] + 1e-16f);
        for (unsigned p = p0 + lane; p < p1; p += 64) {
            int2 se = csr2[p];
            const float* arow = as1 + (size_t)se.x * HEADS;
            #pragma unroll
            for (int h = 0; h < HEADS; ++h) {
                float v = arow[h] + adn[h];
                v = (v >= 0.f) ? v : 0.2f * v;
                float a = __expf(v - m[h]) * inv[h];
                alpha_csr[(size_t)p * HEADS + h] = a;
                alpha_out[(size_t)se.y * HEADS + h] = a;
            }
        }
    }
}

// ---------------- aggregation L1 + elu -> h1b: R8 winner (160 thr, bf16x8/thread) ----
__global__ __launch_bounds__(160) void agg1_kernel(
        const unsigned* __restrict__ offsets, const int2* __restrict__ csr2,
        const float* __restrict__ alpha_csr, const __bf16* __restrict__ h1pb,
        const float* __restrict__ b1, __bf16* __restrict__ h1b, int N) {
    __shared__ float a_lds[64 * HEADS];
    __shared__ int s_lds[64];
    int n = blockIdx.x;
    unsigned p0 = offsets[n], p1 = offsets[n + 1];
    int tid = threadIdx.x;
    const int col = tid * 8;        // thread owns cols [col, col+8) -- all in head tid>>4
    const int hd = tid >> 4;
    float acc[8] = {};
    for (unsigned base = p0; base < p1; base += 64) {
        int cnt = (int)min(64u, p1 - base);
        for (int idx = tid; idx < cnt * HEADS; idx += 160)
            a_lds[idx] = alpha_csr[(size_t)base * HEADS + idx];
        for (int idx = tid; idx < cnt; idx += 160) s_lds[idx] = csr2[base + idx].x;
        __syncthreads();
        #pragma unroll 2
        for (int j = 0; j < cnt; ++j) {
            bf16x8 hv = *(const bf16x8*)(h1pb + (size_t)s_lds[j] * HC + col);
            float a = a_lds[j * HEADS + hd];
            #pragma unroll
            for (int k = 0; k < 8; ++k) acc[k] += (float)hv[k] * a;
        }
        __syncthreads();
    }
    const float4 bv0 = *(const float4*)(b1 + col);
    const float4 bv1 = *(const float4*)(b1 + col + 4);
    float vb[8] = {bv0.x, bv0.y, bv0.z, bv0.w, bv1.x, bv1.y, bv1.z, bv1.w};
    bf16x8 outv;
    #pragma unroll
    for (int k = 0; k < 8; ++k) {
        float v = acc[k] + vb[k];
        v = (v > 0.f) ? v : expm1f(v);
        outv[k] = (__bf16)v;
    }
    *(bf16x8*)(h1b + (size_t)n * HC + col) = outv;
}

// ---------------- fused softmax2 + aggregation L2 + elu + max-pool ----------------
// 4 waves split the edges; bf16x2 loads; cross-wave LDS reduce.
__device__ __forceinline__ unsigned enc_f(float f) {
    unsigned b = __float_as_uint(f);
    return (b & 0x80000000u) ? ~b : (b | 0x80000000u);
}
__device__ __forceinline__ float dec_f(unsigned k) {
    return (k & 0x80000000u) ? __uint_as_float(k & 0x7FFFFFFFu) : __uint_as_float(~k);
}

__global__ __launch_bounds__(256) void agg2_kernel(
        const unsigned* __restrict__ offsets, const int2* __restrict__ csr2,
        const float* __restrict__ as2, const float* __restrict__ ad2,
        const __bf16* __restrict__ h2b, const float* __restrict__ b2,
        const int* __restrict__ batch, unsigned* __restrict__ pooled_u, int N) {
    __shared__ float red[4][128];
    const int n = blockIdx.x;
    const int tid = threadIdx.x;
    const int wv = tid >> 6;        // 0..3
    const int lane = tid & 63;
    const int col = lane * 2;       // this lane accumulates cols col, col+1
    const unsigned p0 = offsets[n], p1 = offsets[n + 1];
    const int deg = (int)(p1 - p0);
    const float adn = ad2[n];
    float acc0 = 0.f, acc1 = 0.f;

    if (deg <= 64) {
        // all 4 waves redundantly compute softmax stats in lane registers
        int s_reg = 0;
        float e_reg = -INFINITY;
        if (lane < deg) {
            s_reg = csr2[p0 + lane].x;
            float v = as2[s_reg] + adn;
            e_reg = (v >= 0.f) ? v : 0.2f * v;
        }
        float m = e_reg;
        #pragma unroll
        for (int off = 32; off; off >>= 1) m = fmaxf(m, __shfl_xor(m, off));
        float ex = (lane < deg) ? __expf(e_reg - m) : 0.f;
        float den = ex;
        #pragma unroll
        for (int off = 32; off; off >>= 1) den += __shfl_xor(den, off);
        float inv = 1.f / (den + 1e-16f);
        // wave wv handles edges wv, wv+4, ...
        for (int j = wv; j < deg; j += 4) {
            int sj = __shfl(s_reg, j);
            float aj = __shfl(ex, j) * inv;
            bf16x2 hv = *(const bf16x2*)(h2b + (size_t)sj * CDIM + col);
            acc0 += (float)hv[0] * aj;
            acc1 += (float)hv[1] * aj;
        }
    } else {
        float m = -INFINITY;
        for (unsigned p = p0 + lane; p < p1; p += 64) {
            float v = as2[csr2[p].x] + adn;
            v = (v >= 0.f) ? v : 0.2f * v;
            m = fmaxf(m, v);
        }
        #pragma unroll
        for (int off = 32; off; off >>= 1) m = fmaxf(m, __shfl_xor(m, off));
        float den = 0.f;
        for (unsigned p = p0 + lane; p < p1; p += 64) {
            float v = as2[csr2[p].x] + adn;
            v = (v >= 0.f) ? v : 0.2f * v;
            den += __expf(v - m);
        }
        #pragma unroll
        for (int off = 32; off; off >>= 1) den += __shfl_xor(den, off);
        float inv = 1.f / (den + 1e-16f);
        for (unsigned p = p0 + wv; p < p1; p += 4) {
            int sj = csr2[p].x;
            float v = as2[sj] + adn;
            v = (v >= 0.f) ? v : 0.2f * v;
            float aj = __expf(v - m) * inv;
            bf16x2 hv = *(const bf16x2*)(h2b + (size_t)sj * CDIM + col);
            acc0 += (float)hv[0] * aj;
            acc1 += (float)hv[1] * aj;
        }
    }
    red[wv][col] = acc0;
    red[wv][col + 1] = acc1;
    __syncthreads();
    if (tid < 128) {
        float v = red[0][tid] + red[1][tid] + red[2][tid] + red[3][tid] + b2[tid];
        v = (v > 0.f) ? v : expm1f(v);
        atomicMax(&pooled_u[batch[n] * CDIM + tid], enc_f(v));
    }
}

__global__ void pool_write_kernel(const unsigned* __restrict__ pooled_u, float* __restrict__ out) {
    int t = blockIdx.x * 256 + threadIdx.x;
    if (t < GRAPHS * CDIM) out[t] = dec_f(pooled_u[t]);
}

extern "C" void kernel_launch(void* const* d_in, const int* in_sizes, int n_in,
                              void* d_out, int out_size, void* d_ws, size_t ws_size,
                              hipStream_t stream) {
    const float* x     = (const float*)d_in[0];
    const int*   ei    = (const int*)d_in[1];
    const int*   batch = (const int*)d_in[2];
    const float* W1    = (const float*)d_in[3];
    const float* asrc1 = (const float*)d_in[4];
    const float* adst1 = (const float*)d_in[5];
    const float* b1    = (const float*)d_in[6];
    const float* W2    = (const float*)d_in[7];
    const float* asrc2 = (const float*)d_in[8];
    const float* adst2 = (const float*)d_in[9];
    const float* b2    = (const float*)d_in[10];
    float* out = (float*)d_out;

    const int N  = in_sizes[0] / FIN;
    const int E  = in_sizes[1] / 2;
    const int Et = E + N;
    const int Mpad = ((N + 127) / 128) * 128;

    char* w = (char*)d_ws;
    auto alloc = [&](size_t nbytes) {
        char* p = w;
        w += (nbytes + 255) & ~(size_t)255;
        return p;
    };
    __bf16* h1pb = (__bf16*)alloc((size_t)N * HC * 2);
    __bf16* h1b  = (__bf16*)alloc((size_t)N * HC * 2);
    __bf16* xb   = (__bf16*)alloc((size_t)Mpad * KP * 2);
    __bf16* W1t  = (__bf16*)alloc((size_t)HC * KP * 2);
    __bf16* W2t  = (__bf16*)alloc((size_t)CDIM * HC * 2);
    float*  Cpart = (float*)alloc((size_t)2 * N * CDIM * 4);
    __bf16* h2b  = (__bf16*)alloc((size_t)N * CDIM * 2);
    float*  as1  = (float*)alloc((size_t)N * HEADS * 4);
    float*  ad1  = (float*)alloc((size_t)N * HEADS * 4);
    float*  as2  = (float*)alloc((size_t)N * 4);
    float*  ad2  = (float*)alloc((size_t)N * 4);
    float*  alpha_csr = (float*)alloc((size_t)Et * HEADS * 4);
    unsigned* counts  = (unsigned*)alloc((size_t)N * 4);
    unsigned* cursor  = (unsigned*)alloc((size_t)N * 4);
    unsigned* offsets = (unsigned*)alloc((size_t)(N + 1) * 4);
    int2* csr2 = (int2*)alloc((size_t)Et * 8);
    unsigned* pooled_u = (unsigned*)alloc((size_t)GRAPHS * CDIM * 4);

    float* alpha_out = out + GRAPHS * CDIM;  // alpha1 region of d_out

    const int init_work = Mpad * KP;
    init_kernel<<<(init_work + 255) / 256, 256, 0, stream>>>(
        counts, cursor, pooled_u, as1, ad1, x, xb, W1, W1t, W2, W2t, N, Mpad);

    gemm1_mfma_kernel<<<dim3(Mpad / 128, HEADS), 256, 0, stream>>>(
        xb, W1t, asrc1, adst1, h1pb, as1, ad1, N);

    hist_kernel<<<(E + 255) / 256, 256, 0, stream>>>(ei, E, counts);
    scan_kernel<<<1, 1024, 0, stream>>>(counts, offsets, N);
    scatter_kernel<<<(Et + 255) / 256, 256, 0, stream>>>(ei, E, N, offsets, cursor, csr2);

    softmax1_kernel<<<(N + 3) / 4, 256, 0, stream>>>(
        offsets, csr2, as1, ad1, alpha_out, alpha_csr, N);
    agg1_kernel<<<N, 160, 0, stream>>>(offsets, csr2, alpha_csr, h1pb, b1, h1b, N);

    gemm2_mfma_kernel<<<dim3((N + 63) / 64, 1, 2), 256, 0, stream>>>(
        h1b, W2t, Cpart, N);
    combine_kernel<<<(N + 3) / 4, 256, 0, stream>>>(Cpart, asrc2, adst2, h2b, as2, ad2, N);

    agg2_kernel<<<N, 256, 0, stream>>>(offsets, csr2, as2, ad2, h2b, b2, batch, pooled_u, N);

    pool_write_kernel<<<(GRAPHS * CDIM + 255) / 256, 256, 0, stream>>>(pooled_u, out);
}

// Round 15
// 265.579 us; speedup vs baseline: 1.0667x; 1.0667x over previous
//
#include <hip/hip_runtime.h>
#include <hip/hip_bf16.h>

#define FIN 78
#define CDIM 128
#define HEADS 10
#define HC 1280
#define GRAPHS 64
#define KP 96   // padded K for layer-1

typedef __bf16 bf16x8 __attribute__((ext_vector_type(8)));
typedef __bf16 bf16x2 __attribute__((ext_vector_type(2)));
typedef float f32x4 __attribute__((ext_vector_type(4)));

// ---------------- init: zero bufs + pack xb/W1t/W2t ----------------
__global__ void init_kernel(unsigned* counts, unsigned* cursor, unsigned* pooled_u,
                            float* as1, float* ad1,
                            const float* __restrict__ x, __bf16* __restrict__ xb,
                            const float* __restrict__ W1, __bf16* __restrict__ W1t,
                            const float* __restrict__ W2, __bf16* __restrict__ W2t,
                            int N, int Mpad) {
    int t = blockIdx.x * 256 + threadIdx.x;
    if (t < N) { counts[t] = 0u; cursor[t] = 0u; }
    if (t < GRAPHS * CDIM) pooled_u[t] = 0x007FFFFFu;  // enc(-inf)
    if (t < N * HEADS) { as1[t] = 0.f; ad1[t] = 0.f; }
    if (t < Mpad * KP) {
        int m = t / KP, k = t % KP;
        float v = (m < N && k < FIN) ? x[(size_t)m * FIN + k] : 0.f;
        xb[t] = (__bf16)v;
    }
    if (t < HC * KP) {
        int n = t / KP, k = t % KP;
        float v = (k < FIN) ? W1[(size_t)k * HC + n] : 0.f;
        W1t[t] = (__bf16)v;
    }
    if (t < CDIM * HC) {
        int n = t / HC, k = t % HC;
        W2t[t] = (__bf16)W2[(size_t)k * CDIM + n];
    }
}

// histogram MUST be a separate launch: it reads counts zeroed by init_kernel.
__global__ void hist_kernel(const int* __restrict__ ei, int E, unsigned* counts) {
    int e = blockIdx.x * 256 + threadIdx.x;
    if (e < E) atomicAdd(&counts[ei[E + e]], 1u);
}

// ---------------- layer-1 GEMM: 128x128x96 bf16 MFMA + fused scores + LDS-staged store
__global__ __launch_bounds__(256) void gemm1_mfma_kernel(
        const __bf16* __restrict__ xb, const __bf16* __restrict__ W1t,
        const float* __restrict__ asrc, const float* __restrict__ adst,
        __bf16* __restrict__ h1pb, float* __restrict__ as1, float* __restrict__ ad1,
        int M) {
    __shared__ __align__(16) __bf16 smem[2 * 128 * 104];   // A/B staging; reused for C
    auto Alds = (__bf16 (*)[104])smem;
    auto Blds = (__bf16 (*)[104])(smem + 128 * 104);
    const int tid = threadIdx.x;
    const int wave = tid >> 6, lane = tid & 63;
    const int wr = wave >> 1, wc = wave & 1;
    const int m0 = blockIdx.x * 128;
    const int head = blockIdx.y;
    const int n0 = head * CDIM;
    const int fl = lane & 15;
    const int fh = lane >> 4;

    for (int idx = tid; idx < 128 * 12; idx += 256) {
        int r = idx / 12, ks = (idx % 12) * 8;
        *(bf16x8*)&Alds[r][ks] = *(const bf16x8*)(xb + (size_t)(m0 + r) * KP + ks);
        *(bf16x8*)&Blds[r][ks] = *(const bf16x8*)(W1t + (size_t)(n0 + r) * KP + ks);
    }
    __syncthreads();

    f32x4 acc[4][4] = {};
    #pragma unroll
    for (int ks = 0; ks < KP; ks += 32) {
        bf16x8 a[4], b[4];
        #pragma unroll
        for (int t = 0; t < 4; ++t) {
            a[t] = *(const bf16x8*)&Alds[wr * 64 + t * 16 + fl][ks + fh * 8];
            b[t] = *(const bf16x8*)&Blds[wc * 64 + t * 16 + fl][ks + fh * 8];
        }
        #pragma unroll
        for (int i = 0; i < 4; ++i)
            #pragma unroll
            for (int j = 0; j < 4; ++j)
                acc[i][j] = __builtin_amdgcn_mfma_f32_16x16x32_bf16(a[i], b[j], acc[i][j], 0, 0, 0);
    }

    float a_s[4], a_d[4];
    #pragma unroll
    for (int j = 0; j < 4; ++j) {
        int gn = n0 + wc * 64 + j * 16 + fl;
        a_s[j] = asrc[gn];
        a_d[j] = adst[gn];
    }
    #pragma unroll
    for (int i = 0; i < 4; ++i) {
        #pragma unroll
        for (int r = 0; r < 4; ++r) {
            int gm = m0 + wr * 64 + i * 16 + fh * 4 + r;
            float vs = 0.f, vd = 0.f;
            #pragma unroll
            for (int j = 0; j < 4; ++j) {
                vs += acc[i][j][r] * a_s[j];
                vd += acc[i][j][r] * a_d[j];
            }
            #pragma unroll
            for (int off = 1; off < 16; off <<= 1) {
                vs += __shfl_xor(vs, off);
                vd += __shfl_xor(vd, off);
            }
            if (fl == 0 && gm < M) {
                atomicAdd(&as1[gm * HEADS + head], vs);
                atomicAdd(&ad1[gm * HEADS + head], vd);
            }
        }
    }

    __syncthreads();
    auto Cst = (__bf16 (*)[136])smem;
    #pragma unroll
    for (int i = 0; i < 4; ++i)
        #pragma unroll
        for (int j = 0; j < 4; ++j)
            #pragma unroll
            for (int r = 0; r < 4; ++r)
                Cst[wr * 64 + i * 16 + fh * 4 + r][wc * 64 + j * 16 + fl] = (__bf16)acc[i][j][r];
    __syncthreads();
    for (int idx = tid; idx < 128 * 16; idx += 256) {
        int r = idx >> 4, v = (idx & 15) * 8;
        int gm = m0 + r;
        if (gm < M)
            *(bf16x8*)(h1pb + (size_t)gm * HC + n0 + v) = *(const bf16x8*)&Cst[r][v];
    }
}

// ---------------- layer-2 GEMM: split-K=2, partial buffers, LDS-staged f32 stores ----
__global__ __launch_bounds__(256) void gemm2_mfma_kernel(
        const __bf16* __restrict__ A, const __bf16* __restrict__ W2t,
        float* __restrict__ Cpart, int M) {
    constexpr int BK = 64;
    constexpr int KCHUNK = HC / 2;  // 640
    __shared__ __align__(16) __bf16 smem[2 * 64 * 72];
    auto Alds = (__bf16 (*)[72])smem;
    auto Blds = (__bf16 (*)[72])(smem + 64 * 72);
    const int tid = threadIdx.x;
    const int wave = tid >> 6, lane = tid & 63;
    const int wr = wave >> 1, wc = wave & 1;
    const int m0 = blockIdx.x * 64;
    const int n0 = blockIdx.y * 64;
    const int kbase = blockIdx.z * KCHUNK;

    const int kslot = (tid & 7) * 8;
    const int srow  = tid >> 3;
    const int fl = lane & 15;
    const int fh = lane >> 4;

    f32x4 acc[2][2] = {};

    for (int k0 = kbase; k0 < kbase + KCHUNK; k0 += BK) {
        #pragma unroll
        for (int rp = 0; rp < 2; ++rp) {
            int r = srow + rp * 32;
            int gm = m0 + r;
            bf16x8 va = {};
            if (gm < M) va = *(const bf16x8*)(A + (size_t)gm * HC + k0 + kslot);
            *(bf16x8*)&Alds[r][kslot] = va;
            *(bf16x8*)&Blds[r][kslot] = *(const bf16x8*)(W2t + (size_t)(n0 + r) * HC + k0 + kslot);
        }
        __syncthreads();
        #pragma unroll
        for (int ks = 0; ks < BK; ks += 32) {
            bf16x8 a[2], b[2];
            #pragma unroll
            for (int t = 0; t < 2; ++t) {
                a[t] = *(const bf16x8*)&Alds[wr * 32 + t * 16 + fl][ks + fh * 8];
                b[t] = *(const bf16x8*)&Blds[wc * 32 + t * 16 + fl][ks + fh * 8];
            }
            #pragma unroll
            for (int i = 0; i < 2; ++i)
                #pragma unroll
                for (int j = 0; j < 2; ++j)
                    acc[i][j] = __builtin_amdgcn_mfma_f32_16x16x32_bf16(a[i], b[j], acc[i][j], 0, 0, 0);
        }
        __syncthreads();
    }
    auto CstF = (float (*)[68])smem;
    #pragma unroll
    for (int i = 0; i < 2; ++i)
        #pragma unroll
        for (int j = 0; j < 2; ++j)
            #pragma unroll
            for (int r = 0; r < 4; ++r)
                CstF[wr * 32 + i * 16 + fh * 4 + r][wc * 32 + j * 16 + fl] = acc[i][j][r];
    __syncthreads();
    float* base = Cpart + (size_t)blockIdx.z * M * CDIM;
    for (int idx = tid; idx < 64 * 16; idx += 256) {
        int r = idx >> 4, c = (idx & 15) * 4;
        int gm = m0 + r;
        if (gm < M)
            *(f32x4*)(base + (size_t)gm * CDIM + n0 + c) = *(const f32x4*)&CstF[r][c];
    }
}

// ---------------- combine split-K partials -> h2b (bf16) + exact scores2 -------------
__global__ __launch_bounds__(256) void combine_kernel(
        const float* __restrict__ Cpart, const float* __restrict__ asrc2,
        const float* __restrict__ adst2, __bf16* __restrict__ h2b,
        float* __restrict__ as2, float* __restrict__ ad2, int N) {
    const int lane = threadIdx.x & 63, wave = threadIdx.x >> 6;
    const int n = blockIdx.x * 4 + wave;
    if (n >= N) return;
    const float* p0 = Cpart + (size_t)n * CDIM;
    const float* p1 = Cpart + (size_t)(N + n) * CDIM;
    float v0 = p0[lane] + p1[lane];
    float v1 = p0[lane + 64] + p1[lane + 64];
    h2b[(size_t)n * CDIM + lane] = (__bf16)v0;
    h2b[(size_t)n * CDIM + lane + 64] = (__bf16)v1;
    float vs = v0 * asrc2[lane] + v1 * asrc2[lane + 64];
    float vd = v0 * adst2[lane] + v1 * adst2[lane + 64];
    #pragma unroll
    for (int off = 32; off; off >>= 1) {
        vs += __shfl_xor(vs, off);
        vd += __shfl_xor(vd, off);
    }
    if (lane == 0) { as2[n] = vs; ad2[n] = vd; }
}

// ---------------- CSR build ----------------
__global__ void scan_kernel(const unsigned* __restrict__ counts, unsigned* __restrict__ offsets, int n) {
    __shared__ unsigned part[1024];
    int t = threadIdx.x;
    int chunk = (n + 1023) / 1024;
    int lo = t * chunk, hi = min(lo + chunk, n);
    unsigned s = 0;
    for (int i = lo; i < hi; ++i) s += counts[i] + 1u;   // +1 self-loop per node
    part[t] = s;
    __syncthreads();
    for (int d = 1; d < 1024; d <<= 1) {
        unsigned v = (t >= d) ? part[t - d] : 0u;
        __syncthreads();
        part[t] += v;
        __syncthreads();
    }
    unsigned base = (t == 0) ? 0u : part[t - 1];
    for (int i = lo; i < hi; ++i) { offsets[i] = base; base += counts[i] + 1u; }
    if (t == 1023) offsets[n] = part[1023];
}

__global__ void scatter_kernel(const int* __restrict__ ei, int E, int N,
                               const unsigned* __restrict__ offsets, unsigned* cursor,
                               int2* __restrict__ csr2) {
    int e = blockIdx.x * 256 + threadIdx.x;
    int Et = E + N;
    if (e >= Et) return;
    int s, d;
    if (e < E) { s = ei[e]; d = ei[E + e]; } else { s = e - E; d = e - E; }
    unsigned pos = offsets[d] + atomicAdd(&cursor[d], 1u);
    csr2[pos] = make_int2(s, e);
}

// ---------------- segment softmax L1: one wave per node ----------------
__global__ __launch_bounds__(256) void softmax1_kernel(
        const unsigned* __restrict__ offsets, const int2* __restrict__ csr2,
        const float* __restrict__ as1, const float* __restrict__ ad1,
        float* __restrict__ alpha_out, float* __restrict__ alpha_csr, int N) {
    const int wave = threadIdx.x >> 6, lane = threadIdx.x & 63;
    const int n = blockIdx.x * 4 + wave;
    if (n >= N) return;
    const unsigned p0 = offsets[n], p1 = offsets[n + 1];
    const unsigned deg = p1 - p0;

    float adn[HEADS];
    #pragma unroll
    for (int h = 0; h < HEADS; ++h) adn[h] = ad1[n * HEADS + h];

    if (deg <= 64) {
        const bool act = lane < (int)deg;
        const unsigned p = p0 + lane;
        int s = 0, eid = 0;
        if (act) { int2 se = csr2[p]; s = se.x; eid = se.y; }
        const float* arow = as1 + (size_t)s * HEADS;
        float e[HEADS];
        #pragma unroll
        for (int h = 0; h < HEADS; ++h) {
            float v = act ? (arow[h] + adn[h]) : -INFINITY;
            e[h] = (v >= 0.f) ? v : 0.2f * v;
        }
        float m[HEADS];
        #pragma unroll
        for (int h = 0; h < HEADS; ++h) m[h] = e[h];
        #pragma unroll
        for (int off = 32; off; off >>= 1)
            #pragma unroll
            for (int h = 0; h < HEADS; ++h) m[h] = fmaxf(m[h], __shfl_xor(m[h], off));
        float ex[HEADS], sm[HEADS];
        #pragma unroll
        for (int h = 0; h < HEADS; ++h) {
            ex[h] = act ? __expf(e[h] - m[h]) : 0.f;
            sm[h] = ex[h];
        }
        #pragma unroll
        for (int off = 32; off; off >>= 1)
            #pragma unroll
            for (int h = 0; h < HEADS; ++h) sm[h] += __shfl_xor(sm[h], off);
        if (act) {
            #pragma unroll
            for (int h = 0; h < HEADS; ++h) {
                float a = ex[h] / (sm[h] + 1e-16f);
                alpha_csr[(size_t)p * HEADS + h] = a;
                alpha_out[(size_t)eid * HEADS + h] = a;
            }
        }
    } else {
        float m[HEADS];
        #pragma unroll
        for (int h = 0; h < HEADS; ++h) m[h] = -INFINITY;
        for (unsigned p = p0 + lane; p < p1; p += 64) {
            const float* arow = as1 + (size_t)csr2[p].x * HEADS;
            #pragma unroll
            for (int h = 0; h < HEADS; ++h) {
                float v = arow[h] + adn[h];
                v = (v >= 0.f) ? v : 0.2f * v;
                m[h] = fmaxf(m[h], v);
            }
        }
        #pragma unroll
        for (int off = 32; off; off >>= 1)
            #pragma unroll
            for (int h = 0; h < HEADS; ++h) m[h] = fmaxf(m[h], __shfl_xor(m[h], off));
        float sm[HEADS];
        #pragma unroll
        for (int h = 0; h < HEADS; ++h) sm[h] = 0.f;
        for (unsigned p = p0 + lane; p < p1; p += 64) {
            const float* arow = as1 + (size_t)csr2[p].x * HEADS;
            #pragma unroll
            for (int h = 0; h < HEADS; ++h) {
                float v = arow[h] + adn[h];
                v = (v >= 0.f) ? v : 0.2f * v;
                sm[h] += __expf(v - m[h]);
            }
        }
        #pragma unroll
        for (int off = 32; off; off >>= 1)
            #pragma unroll
            for (int h = 0; h < HEADS; ++h) sm[h] += __shfl_xor(sm[h], off);
        float inv[HEADS];
        #pragma unroll
        for (int h = 0; h < HEADS; ++h) inv[h] = 1.f / (sm[h] + 1e-16f);
        for (unsigned p = p0 + lane; p < p1; p += 64) {
            int2 se = csr2[p];
            const float* arow = as1 + (size_t)se.x * HEADS;
            #pragma unroll
            for (int h = 0; h < HEADS; ++h) {
                float v = arow[h] + adn[h];
                v = (v >= 0.f) ? v : 0.2f * v;
                float a = __expf(v - m[h]) * inv[h];
                alpha_csr[(size_t)p * HEADS + h] = a;
                alpha_out[(size_t)se.y * HEADS + h] = a;
            }
        }
    }
}

// ---------------- aggregation L1 + elu -> h1b: R8 winner (160 thr, bf16x8/thread) ----
__global__ __launch_bounds__(160) void agg1_kernel(
        const unsigned* __restrict__ offsets, const int2* __restrict__ csr2,
        const float* __restrict__ alpha_csr, const __bf16* __restrict__ h1pb,
        const float* __restrict__ b1, __bf16* __restrict__ h1b, int N) {
    __shared__ float a_lds[64 * HEADS];
    __shared__ int s_lds[64];
    int n = blockIdx.x;
    unsigned p0 = offsets[n], p1 = offsets[n + 1];
    int tid = threadIdx.x;
    const int col = tid * 8;        // thread owns cols [col, col+8) -- all in head tid>>4
    const int hd = tid >> 4;
    float acc[8] = {};
    for (unsigned base = p0; base < p1; base += 64) {
        int cnt = (int)min(64u, p1 - base);
        for (int idx = tid; idx < cnt * HEADS; idx += 160)
            a_lds[idx] = alpha_csr[(size_t)base * HEADS + idx];
        for (int idx = tid; idx < cnt; idx += 160) s_lds[idx] = csr2[base + idx].x;
        __syncthreads();
        #pragma unroll 2
        for (int j = 0; j < cnt; ++j) {
            bf16x8 hv = *(const bf16x8*)(h1pb + (size_t)s_lds[j] * HC + col);
            float a = a_lds[j * HEADS + hd];
            #pragma unroll
            for (int k = 0; k < 8; ++k) acc[k] += (float)hv[k] * a;
        }
        __syncthreads();
    }
    const float4 bv0 = *(const float4*)(b1 + col);
    const float4 bv1 = *(const float4*)(b1 + col + 4);
    float vb[8] = {bv0.x, bv0.y, bv0.z, bv0.w, bv1.x, bv1.y, bv1.z, bv1.w};
    bf16x8 outv;
    #pragma unroll
    for (int k = 0; k < 8; ++k) {
        float v = acc[k] + vb[k];
        v = (v > 0.f) ? v : expm1f(v);
        outv[k] = (__bf16)v;
    }
    *(bf16x8*)(h1b + (size_t)n * HC + col) = outv;
}

// ---------------- fused softmax2 + aggregation L2 + elu + max-pool ----------------
// 2 waves split the edges; bf16x2 loads; cross-wave LDS reduce.
__device__ __forceinline__ unsigned enc_f(float f) {
    unsigned b = __float_as_uint(f);
    return (b & 0x80000000u) ? ~b : (b | 0x80000000u);
}
__device__ __forceinline__ float dec_f(unsigned k) {
    return (k & 0x80000000u) ? __uint_as_float(k & 0x7FFFFFFFu) : __uint_as_float(~k);
}

__global__ __launch_bounds__(128) void agg2_kernel(
        const unsigned* __restrict__ offsets, const int2* __restrict__ csr2,
        const float* __restrict__ as2, const float* __restrict__ ad2,
        const __bf16* __restrict__ h2b, const float* __restrict__ b2,
        const int* __restrict__ batch, unsigned* __restrict__ pooled_u, int N) {
    __shared__ float red[2][128];
    const int n = blockIdx.x;
    const int tid = threadIdx.x;
    const int wv = tid >> 6;        // 0 or 1
    const int lane = tid & 63;
    const int col = lane * 2;       // this lane accumulates cols col, col+1
    const unsigned p0 = offsets[n], p1 = offsets[n + 1];
    const int deg = (int)(p1 - p0);
    const float adn = ad2[n];
    float acc0 = 0.f, acc1 = 0.f;

    if (deg <= 64) {
        // both waves redundantly compute softmax stats in lane registers
        int s_reg = 0;
        float e_reg = -INFINITY;
        if (lane < deg) {
            s_reg = csr2[p0 + lane].x;
            float v = as2[s_reg] + adn;
            e_reg = (v >= 0.f) ? v : 0.2f * v;
        }
        float m = e_reg;
        #pragma unroll
        for (int off = 32; off; off >>= 1) m = fmaxf(m, __shfl_xor(m, off));
        float ex = (lane < deg) ? __expf(e_reg - m) : 0.f;
        float den = ex;
        #pragma unroll
        for (int off = 32; off; off >>= 1) den += __shfl_xor(den, off);
        float inv = 1.f / (den + 1e-16f);
        // wave wv handles edges wv, wv+2, ...
        for (int j = wv; j < deg; j += 2) {
            int sj = __shfl(s_reg, j);
            float aj = __shfl(ex, j) * inv;
            bf16x2 hv = *(const bf16x2*)(h2b + (size_t)sj * CDIM + col);
            acc0 += (float)hv[0] * aj;
            acc1 += (float)hv[1] * aj;
        }
    } else {
        float m = -INFINITY;
        for (unsigned p = p0 + lane; p < p1; p += 64) {
            float v = as2[csr2[p].x] + adn;
            v = (v >= 0.f) ? v : 0.2f * v;
            m = fmaxf(m, v);
        }
        #pragma unroll
        for (int off = 32; off; off >>= 1) m = fmaxf(m, __shfl_xor(m, off));
        float den = 0.f;
        for (unsigned p = p0 + lane; p < p1; p += 64) {
            float v = as2[csr2[p].x] + adn;
            v = (v >= 0.f) ? v : 0.2f * v;
            den += __expf(v - m);
        }
        #pragma unroll
        for (int off = 32; off; off >>= 1) den += __shfl_xor(den, off);
        float inv = 1.f / (den + 1e-16f);
        for (unsigned p = p0 + wv; p < p1; p += 2) {
            int sj = csr2[p].x;
            float v = as2[sj] + adn;
            v = (v >= 0.f) ? v : 0.2f * v;
            float aj = __expf(v - m) * inv;
            bf16x2 hv = *(const bf16x2*)(h2b + (size_t)sj * CDIM + col);
            acc0 += (float)hv[0] * aj;
            acc1 += (float)hv[1] * aj;
        }
    }
    red[wv][col] = acc0;
    red[wv][col + 1] = acc1;
    __syncthreads();
    float v = red[0][tid] + red[1][tid] + b2[tid];
    v = (v > 0.f) ? v : expm1f(v);
    atomicMax(&pooled_u[batch[n] * CDIM + tid], enc_f(v));
}

__global__ void pool_write_kernel(const unsigned* __restrict__ pooled_u, float* __restrict__ out) {
    int t = blockIdx.x * 256 + threadIdx.x;
    if (t < GRAPHS * CDIM) out[t] = dec_f(pooled_u[t]);
}

extern "C" void kernel_launch(void* const* d_in, const int* in_sizes, int n_in,
                              void* d_out, int out_size, void* d_ws, size_t ws_size,
                              hipStream_t stream) {
    const float* x     = (const float*)d_in[0];
    const int*   ei    = (const int*)d_in[1];
    const int*   batch = (const int*)d_in[2];
    const float* W1    = (const float*)d_in[3];
    const float* asrc1 = (const float*)d_in[4];
    const float* adst1 = (const float*)d_in[5];
    const float* b1    = (const float*)d_in[6];
    const float* W2    = (const float*)d_in[7];
    const float* asrc2 = (const float*)d_in[8];
    const float* adst2 = (const float*)d_in[9];
    const float* b2    = (const float*)d_in[10];
    float* out = (float*)d_out;

    const int N  = in_sizes[0] / FIN;
    const int E  = in_sizes[1] / 2;
    const int Et = E + N;
    const int Mpad = ((N + 127) / 128) * 128;

    char* w = (char*)d_ws;
    auto alloc = [&](size_t nbytes) {
        char* p = w;
        w += (nbytes + 255) & ~(size_t)255;
        return p;
    };
    __bf16* h1pb = (__bf16*)alloc((size_t)N * HC * 2);
    __bf16* h1b  = (__bf16*)alloc((size_t)N * HC * 2);
    __bf16* xb   = (__bf16*)alloc((size_t)Mpad * KP * 2);
    __bf16* W1t  = (__bf16*)alloc((size_t)HC * KP * 2);
    __bf16* W2t  = (__bf16*)alloc((size_t)CDIM * HC * 2);
    float*  Cpart = (float*)alloc((size_t)2 * N * CDIM * 4);
    __bf16* h2b  = (__bf16*)alloc((size_t)N * CDIM * 2);
    float*  as1  = (float*)alloc((size_t)N * HEADS * 4);
    float*  ad1  = (float*)alloc((size_t)N * HEADS * 4);
    float*  as2  = (float*)alloc((size_t)N * 4);
    float*  ad2  = (float*)alloc((size_t)N * 4);
    float*  alpha_csr = (float*)alloc((size_t)Et * HEADS * 4);
    unsigned* counts  = (unsigned*)alloc((size_t)N * 4);
    unsigned* cursor  = (unsigned*)alloc((size_t)N * 4);
    unsigned* offsets = (unsigned*)alloc((size_t)(N + 1) * 4);
    int2* csr2 = (int2*)alloc((size_t)Et * 8);
    unsigned* pooled_u = (unsigned*)alloc((size_t)GRAPHS * CDIM * 4);

    float* alpha_out = out + GRAPHS * CDIM;  // alpha1 region of d_out

    const int init_work = Mpad * KP;
    init_kernel<<<(init_work + 255) / 256, 256, 0, stream>>>(
        counts, cursor, pooled_u, as1, ad1, x, xb, W1, W1t, W2, W2t, N, Mpad);

    gemm1_mfma_kernel<<<dim3(Mpad / 128, HEADS), 256, 0, stream>>>(
        xb, W1t, asrc1, adst1, h1pb, as1, ad1, N);

    hist_kernel<<<(E + 255) / 256, 256, 0, stream>>>(ei, E, counts);
    scan_kernel<<<1, 1024, 0, stream>>>(counts, offsets, N);
    scatter_kernel<<<(Et + 255) / 256, 256, 0, stream>>>(ei, E, N, offsets, cursor, csr2);

    softmax1_kernel<<<(N + 3) / 4, 256, 0, stream>>>(
        offsets, csr2, as1, ad1, alpha_out, alpha_csr, N);
    agg1_kernel<<<N, 160, 0, stream>>>(offsets, csr2, alpha_csr, h1pb, b1, h1b, N);

    gemm2_mfma_kernel<<<dim3((N + 63) / 64, CDIM / 64, 2), 256, 0, stream>>>(
        h1b, W2t, Cpart, N);
    combine_kernel<<<(N + 3) / 4, 256, 0, stream>>>(Cpart, asrc2, adst2, h2b, as2, ad2, N);

    agg2_kernel<<<N, 128, 0, stream>>>(offsets, csr2, as2, ad2, h2b, b2, batch, pooled_u, N);

    pool_write_kernel<<<(GRAPHS * CDIM + 255) / 256, 256, 0, stream>>>(pooled_u, out);
}